// Round 16
// baseline (128.559 us; speedup 1.0000x reference)
//
#include <hip/hip_runtime.h>
#include <hip/hip_cooperative_groups.h>
#include <math.h>

namespace cg = cooperative_groups;

#define B_ 32
#define P_ 1000
#define T_ 16
#define D_ 78
#define O_ 72
#define NXB 16            // p-chunks of 64
#define BIGC 100000000.0f

// ================= Fused cooperative kernel: A(k1) -> sync -> B(k2) -> sync -> C(k3) ==========
// 512 blocks x 256 threads, __launch_bounds__(256,2) => 2 blocks/CU co-resident (grid fits).
// Phase A: block (b,bx) computes S[b][t][p0..p0+63] for all 16 t (wave = t-group, full o-loop),
//          per-p scalars (focal, ps0/ps1/pth), per-block partial maxes. (round-14 k1, verified)
// Phase B: block (b,t): cost+S -> LDS, wave-0 LDS-scan top-4 (round-13 k2, verified)
// Phase C: blocks 0..127: conflict resolution from sel/selc (round-13 k3, verified)
__global__ __launch_bounds__(256, 2) void kfused(
        const float* __restrict__ preds, const float* __restrict__ targets,
        const int* __restrict__ masks,
        const int* __restrict__ imgw_p, const int* __restrict__ imgh_p,
        float* __restrict__ Sarr, float4* __restrict__ scal4, float* __restrict__ pths,
        float* __restrict__ pmax, float* __restrict__ cntg,
        int4* __restrict__ sel, float4* __restrict__ selc,
        int* __restrict__ out) {
    cg::grid_group grid = cg::this_grid();
    __shared__ __align__(16) float smem[8192];       // 32 KB, re-carved per phase

    const int g = blockIdx.x;
    const int tid = threadIdx.x;
    const float w = (float)(imgw_p[0] - 1);
    const float h = (float)(imgh_p[0] - 1);

    // ================= PHASE A =================
    {
        float*  pred_s = smem;                        // 5184 floats (64 rows, pad 81)
        float2* tomg   = (float2*)(smem + 5184);      // 1152 float2 (2304 floats)
        float*  cnt_s  = smem + 5184 + 2304;          // 16
        float*  clen_s = cnt_s + 16;                  // 16
        float*  ts0_s  = clen_s + 16;                 // 16
        float*  ts1_s  = ts0_s + 16;                  // 16
        float*  tth_s  = ts1_s + 16;                  // 16
        float*  wmaxf  = tth_s + 16;                  // 12 (4 waves x 3)

        const int b = g >> 4, bx = g & 15;
        const int p0 = bx * 64;
        const int rows = min(64, P_ - p0);
        const float imgwf = (float)imgw_p[0];

        // stage preds rows (coalesced float4); scale col 3 and cols>=6 by w
        {
            const float4* gbase = (const float4*)(preds + ((size_t)b * P_ + p0) * D_);
            const int n4 = rows * D_ / 4;
            for (int i = tid; i < n4; i += 256) {
                float4 v = gbase[i];
                int base = i * 4;
                int r = base / D_, c = base - r * D_;
#pragma unroll
                for (int k = 0; k < 4; ++k) {
                    int cc = c + k, rr = r;
                    if (cc >= D_) { cc -= D_; ++rr; }
                    float x = (&v.x)[k];
                    if (cc >= 6 || cc == 3) x *= w;
                    pred_s[rr * 81 + cc] = x;
                }
            }
        }
        // stage target offsets + masks, packed per (t-group, o)
        for (int i = tid; i < T_ * O_; i += 256) {
            int t = i / O_, o = i - t * O_;
            float to = targets[((size_t)b * T_ + t) * D_ + 6 + o] * w;
            float m = (to >= 0.f && to < imgwf) ? 1.f : 0.f;
            tomg[((t >> 2) * O_ + o) * 4 + (t & 3)] = make_float2(to, m);
        }
        __syncthreads();
        if (tid < T_) {
            int t = tid;
            float c = 0.f;
            for (int o = 0; o < O_; ++o) c += tomg[((t >> 2) * O_ + o) * 4 + (t & 3)].y;
            cnt_s[t] = c;
            clen_s[t] = fmaxf(c, 1.f);
            const float* tr = targets + ((size_t)b * T_ + t) * D_;
            ts0_s[t] = tr[2] * h;
            ts1_s[t] = tr[3] * w;
            tth_s[t] = tr[4];
        }
        __syncthreads();

        if (bx == 0 && tid < T_) cntg[b * T_ + tid] = cnt_s[tid];

        const int lane = tid & 63;
        const int tg = tid >> 6;                   // wave = t-group: t = 4tg..4tg+3
        const int p = p0 + lane;

        float ldm = 0.f, lsm = 0.f, ltm = 0.f;
        if (p < P_) {
            const float* lrow = pred_s + lane * 81;
            const float4* tg4 = (const float4*)(tomg + (size_t)tg * O_ * 4);
            float S0 = 0.f, S1 = 0.f, S2 = 0.f, S3 = 0.f;
#pragma unroll 4
            for (int o = 0; o < O_; ++o) {
                float po = lrow[6 + o];
                float4 r0 = tg4[2 * o];            // (to0,m0,to1,m1) wave-uniform broadcast
                float4 r1 = tg4[2 * o + 1];        // (to2,m2,to3,m3)
                S0 += r0.y * fabsf(po - r0.x);
                S1 += r0.w * fabsf(po - r0.z);
                S2 += r1.y * fabsf(po - r1.x);
                S3 += r1.w * fabsf(po - r1.z);
            }
            float Sv[4] = {S0, S1, S2, S3};
            float ps0 = lrow[2] * h, ps1 = lrow[3], pth = lrow[4];   // col3 pre-scaled by w
#pragma unroll
            for (int j = 0; j < 4; ++j) {
                int t = 4 * tg + j;
                float S = Sv[j];
                Sarr[(size_t)(b * T_ + t) * P_ + p] = S;
                float dv = S / clen_s[t];          // needed only for the dist-max
                ldm = fmaxf(ldm, dv);
                float d0 = ps0 - ts0_s[t], d1 = ps1 - ts1_s[t];
                lsm = fmaxf(lsm, sqrtf(d0 * d0 + d1 * d1));
                ltm = fmaxf(ltm, fabsf(pth - tth_s[t]) * 180.f);
            }
            if (tg == 0) {                         // per-p scalars for phase B
                float fc[2];
#pragma unroll
                for (int c = 0; c < 2; ++c) {
                    float x = lrow[c];
                    float pc = 1.f / (1.f + expf(-x));
                    float neg = -logf(1.f - pc + 1e-12f) * 0.75f * pc * pc;
                    float pos = -logf(pc + 1e-12f) * 0.25f * (1.f - pc) * (1.f - pc);
                    fc[c] = pos - neg;
                }
                scal4[(size_t)b * P_ + p] = make_float4(fc[0], fc[1], ps0, ps1);
                pths[(size_t)b * P_ + p] = pth;
            }
        }

        // per-wave shuffle max (fmax order-invariant -> exact), tiny merge
        for (int off = 32; off; off >>= 1) {
            ldm = fmaxf(ldm, __shfl_xor(ldm, off, 64));
            lsm = fmaxf(lsm, __shfl_xor(lsm, off, 64));
            ltm = fmaxf(ltm, __shfl_xor(ltm, off, 64));
        }
        if (lane == 0) { wmaxf[tg * 3 + 0] = ldm; wmaxf[tg * 3 + 1] = lsm; wmaxf[tg * 3 + 2] = ltm; }
        __syncthreads();
        if (tid == 0) {
            float m0 = 0.f, m1 = 0.f, m2 = 0.f;
#pragma unroll
            for (int i = 0; i < 4; ++i) {
                m0 = fmaxf(m0, wmaxf[i * 3 + 0]);
                m1 = fmaxf(m1, wmaxf[i * 3 + 1]);
                m2 = fmaxf(m2, wmaxf[i * 3 + 2]);
            }
            float* q = pmax + (size_t)(b * NXB + bx) * 3;
            q[0] = m0; q[1] = m1; q[2] = m2;
        }
    }

    grid.sync();

    // ================= PHASE B =================
    {
        float* costL = smem;             // 1024
        float* SL    = smem + 1024;      // 1024

        const int b = g >> 4, t = g & 15;

        float dm = 0.f, sm = 0.f, tm = 0.f;
        for (int i = 0; i < NXB; ++i) {
            const float* q = pmax + (size_t)(b * NXB + i) * 3;
            dm = fmaxf(dm, q[0]); sm = fmaxf(sm, q[1]); tm = fmaxf(tm, q[2]);
        }
        dm = fmaxf(dm, 1e-8f); sm = fmaxf(sm, 1e-8f); tm = fmaxf(tm, 1e-8f);

        const float* tr = targets + (size_t)(b * T_ + t) * D_;
        const float ts0 = tr[2] * h, ts1 = tr[3] * w, tth = tr[4];
        int lab = (int)tr[1]; lab = lab < 0 ? 0 : (lab > 1 ? 1 : lab);
        const int mk = masks[b * T_ + t];
        const float cntv = cntg[b * T_ + t];
        const float clen = fmaxf(cntv, 1.f);
        const float c30 = 30.f * cntv;

        const float* Srow = Sarr + (size_t)(b * T_ + t) * P_;
        const float4* s4b = scal4 + (size_t)b * P_;
        const float* ptb = pths + (size_t)b * P_;

#pragma unroll
        for (int i = 0; i < 4; ++i) {
            int p = tid + 256 * i;
            if (p < P_) {
                float S = Srow[p];
                float4 s4 = s4b[p];
                float pth = ptb[p];
                float dv = S / clen;                      // == phase A's dist, bit-identical
                float dsc = 1.f - dv / dm + 0.01f;
                float d0 = s4.z - ts0, d1 = s4.w - ts1;
                float ssc = 1.f - sqrtf(d0 * d0 + d1 * d1) / sm + 0.01f;
                float tsc = 1.f - fabsf(pth - tth) * 180.f / tm + 0.01f;
                float reg = fmaxf(dsc, 1e-3f) * fmaxf(ssc, 1e-3f) * fmaxf(tsc, 1e-3f);
                float c = -(reg * reg) * 3.f + (lab ? s4.y : s4.x);
                if (mk <= 0) c = BIGC;
                costL[p] = c;
                SL[p] = S;
            } else {
                costL[p] = INFINITY;
                SL[p] = INFINITY;                          // ascending-S scan sentinel
            }
        }
        __syncthreads();

        if (tid < 64) {                          // wave 0 scans (no return: grid.sync below)
            const int lane = tid;

            // bottom-4 S ascending == top-4 liou descending (liou monotone-dec in S)
            float v0, v1, v2, v3;
#define SROUND(vr) { float bv = INFINITY; int bi = 0x7fffffff;            \
            _Pragma("unroll")                                             \
            for (int i = 0; i < 16; ++i) { int ix = lane + 64 * i;        \
                float v = SL[ix];                                         \
                if (v < bv || (v == bv && ix < bi)) { bv = v; bi = ix; } }\
            for (int off = 32; off; off >>= 1) {                          \
                float ov = __shfl_xor(bv, off, 64);                       \
                int oi = __shfl_xor(bi, off, 64);                         \
                if (ov < bv || (ov == bv && oi < bi)) { bv = ov; bi = oi; } } \
            vr = bv; if ((bi & 63) == lane) SL[bi] = INFINITY; }
            SROUND(v0) SROUND(v1) SROUND(v2) SROUND(v3)
#undef SROUND
            float l0 = (c30 - v0) / (c30 + v0 + 1e-9f);
            float l1 = (c30 - v1) / (c30 + v1 + 1e-9f);
            float l2 = (c30 - v2) / (c30 + v2 + 1e-9f);
            float l3 = (c30 - v3) / (c30 + v3 + 1e-9f);
            float sum = ((l0 + l1) + l2) + l3;
            int dk = 0;
            if (mk > 0) {
                dk = (int)sum;                 // trunc toward zero == astype(int32)
                if (dk < 1) dk = 1;
                if (dk > 4) dk = 4;
            }

            // top-4 lowest cost (asc, lower-p tie-break == lax.top_k stable)
            int s0, s1, s2, s3;
            float c0, c1, c2, c3;
#define CROUND(sr, cr) { float bv = INFINITY; int bi = 0x7fffffff;        \
            _Pragma("unroll")                                             \
            for (int i = 0; i < 16; ++i) { int ix = lane + 64 * i;        \
                float v = costL[ix];                                      \
                if (v < bv || (v == bv && ix < bi)) { bv = v; bi = ix; } }\
            for (int off = 32; off; off >>= 1) {                          \
                float ov = __shfl_xor(bv, off, 64);                       \
                int oi = __shfl_xor(bi, off, 64);                         \
                if (ov < bv || (ov == bv && oi < bi)) { bv = ov; bi = oi; } } \
            sr = bi; cr = bv; if ((bi & 63) == lane) costL[bi] = INFINITY; }
            CROUND(s0, c0) CROUND(s1, c1) CROUND(s2, c2) CROUND(s3, c3)
#undef CROUND

            if (lane == 0) {
                sel[g]  = make_int4(dk > 0 ? s0 : -1, dk > 1 ? s1 : -1,
                                    dk > 2 ? s2 : -1, dk > 3 ? s3 : -1);
                selc[g] = make_float4(c0, c1, c2, c3);
            }
        }
    }

    grid.sync();

    // ================= PHASE C =================
    if (g < 128) {
        int*   selE = (int*)smem;        // 64
        float* selC = smem + 64;         // 64

        const int b = g >> 2, cx = g & 3;
        if (tid < 64) {
            selE[tid] = ((const int*)sel)[b * 64 + tid];
            selC[tid] = ((const float*)selc)[b * 64 + tid];
        }
        __syncthreads();

        const int p = cx * 250 + tid;
        if (tid < 250) {
            int matched = -1;
            float best = INFINITY;
#pragma unroll
            for (int t = 0; t < T_; ++t) {
#pragma unroll
                for (int j = 0; j < 4; ++j) {
                    if (selE[4 * t + j] == p) {
                        float c = selC[4 * t + j];
                        if (c < best) { best = c; matched = t; }  // strict <: first-min on t
                    }
                }
            }
            out[b * P_ + p] = (matched >= 0) ? 1 : 0;
            out[B_ * P_ + b * P_ + p] = matched;
        }
    }
}

extern "C" void kernel_launch(void* const* d_in, const int* in_sizes, int n_in,
                              void* d_out, int out_size, void* d_ws, size_t ws_size,
                              hipStream_t stream) {
    const float* preds   = (const float*)d_in[0];
    const float* targets = (const float*)d_in[1];
    const int*   masks   = (const int*)d_in[2];
    const int*   imgw    = (const int*)d_in[3];
    const int*   imgh    = (const int*)d_in[4];
    int* out = (int*)d_out;

    char* ws = (char*)d_ws;
    float*  Sarr  = (float*)ws;                        // [B][T][P]  2,048,000 B
    float4* scal4 = (float4*)(ws + 2048000);           // [B][P]       512,000 B
    float*  pths  = (float*)(ws + 2560000);            // [B][P]       128,000 B
    float*  pmax  = (float*)(ws + 2688000);            // [B][NXB][3]    6,144 B
    float*  cntg  = (float*)(ws + 2694144);            // [B][T]         2,048 B
    int4*   sel   = (int4*)(ws + 2696192);             // [B*T]          8,192 B
    float4* selc  = (float4*)(ws + 2704384);           // [B*T]          8,192 B

    void* args[] = {
        (void*)&preds, (void*)&targets, (void*)&masks, (void*)&imgw, (void*)&imgh,
        (void*)&Sarr, (void*)&scal4, (void*)&pths, (void*)&pmax, (void*)&cntg,
        (void*)&sel, (void*)&selc, (void*)&out
    };
    hipLaunchCooperativeKernel((void*)kfused, dim3(512), dim3(256), args, 0, stream);
}

// Round 18
// 34.398 us; speedup vs baseline: 3.7374x; 3.7374x over previous
//
#include <hip/hip_runtime.h>
#include <math.h>

#define B_ 32
#define P_ 1000
#define T_ 16
#define D_ 78
#define O_ 72
#define NXB 16            // p-chunks of 64
#define BIGC 100000000.0f

// ---------------- K1: masked-L1 sums S + per-p scalars + per-block partial maxes ----------------
// tomg stores a SINGLE float per (t,o): to*w for valid entries, NaN for invalid.
// S += fmaxf(fabsf(po - to'), 0.f): IEEE v_max_f32 returns the non-NaN operand,
// so invalid terms add exactly 0 -> bit-exact vs m*|po-to|. Halves the
// wave-uniform ds_read_b128 broadcast traffic (72 instead of 144 per wave).
// ROUND-17 BUG FIX: per-group float4 base is tomg + tg*O_*4 (288 floats/group),
// not tg*O_ — waves 1..3 were reading garbage.
__global__ __launch_bounds__(256) void k1(
        const float* __restrict__ preds, const float* __restrict__ targets,
        const int* __restrict__ imgw_p, const int* __restrict__ imgh_p,
        float* __restrict__ Sarr, float4* __restrict__ scal4, float* __restrict__ pths,
        float* __restrict__ pmax, float* __restrict__ cntg) {
    __shared__ float pred_s[64 * 81];          // 20.7 KB, pad 81 -> conflict-free rows
    __shared__ float tomg[T_ * O_ * 1];        // 4.6 KB  [g*288 + o*4 + j] = to' (NaN if invalid)
    __shared__ float wmax[4][3];
    __shared__ float cnt_s[T_], clen_s[T_], ts0_s[T_], ts1_s[T_], tth_s[T_];

    const int b = blockIdx.y, bx = blockIdx.x;
    const int p0 = bx * 64;
    const int rows = min(64, P_ - p0);
    const int tid = threadIdx.x;
    const float w = (float)(imgw_p[0] - 1);
    const float h = (float)(imgh_p[0] - 1);
    const float imgwf = (float)imgw_p[0];

    // stage preds rows (coalesced float4); scale col 3 and cols>=6 by w
    {
        const float4* gbase = (const float4*)(preds + ((size_t)b * P_ + p0) * D_);
        const int n4 = rows * D_ / 4;
        for (int i = tid; i < n4; i += 256) {
            float4 v = gbase[i];
            int base = i * 4;
            int r = base / D_, c = base - r * D_;
#pragma unroll
            for (int k = 0; k < 4; ++k) {
                int cc = c + k, rr = r;
                if (cc >= D_) { cc -= D_; ++rr; }
                float x = (&v.x)[k];
                if (cc >= 6 || cc == 3) x *= w;
                pred_s[rr * 81 + cc] = x;
            }
        }
    }
    // stage target offsets: to*w if valid else NaN, packed per (t-group, o)
    for (int i = tid; i < T_ * O_; i += 256) {
        int t = i / O_, o = i - t * O_;
        float to = targets[((size_t)b * T_ + t) * D_ + 6 + o] * w;
        bool valid = (to >= 0.f) && (to < imgwf);
        tomg[((t >> 2) * O_ + o) * 4 + (t & 3)] = valid ? to : __int_as_float(0x7fc00000);
    }
    __syncthreads();
    if (tid < T_) {
        int t = tid;
        float c = 0.f;
        for (int o = 0; o < O_; ++o) {
            float to = tomg[((t >> 2) * O_ + o) * 4 + (t & 3)];
            c += (to == to) ? 1.f : 0.f;       // !isnan == valid
        }
        cnt_s[t] = c;
        clen_s[t] = fmaxf(c, 1.f);
        const float* tr = targets + ((size_t)b * T_ + t) * D_;
        ts0_s[t] = tr[2] * h;
        ts1_s[t] = tr[3] * w;
        tth_s[t] = tr[4];
    }
    __syncthreads();

    if (bx == 0 && tid < T_) cntg[b * T_ + tid] = cnt_s[tid];

    const int lane = tid & 63;
    const int tg = tid >> 6;                   // wave = t-group: t = 4tg..4tg+3
    const int p = p0 + lane;

    float ldm = 0.f, lsm = 0.f, ltm = 0.f;
    if (p < P_) {
        const float* lrow = pred_s + lane * 81;
        const float4* tg4 = (const float4*)(tomg + (size_t)tg * O_ * 4);   // FIXED base
        float S0 = 0.f, S1 = 0.f, S2 = 0.f, S3 = 0.f;
#pragma unroll 4
        for (int o = 0; o < O_; ++o) {
            float po = lrow[6 + o];
            float4 tv = tg4[o];                // (to'_t0..to'_t3) wave-uniform broadcast
            S0 += fmaxf(fabsf(po - tv.x), 0.f);   // NaN -> 0 (IEEE max)
            S1 += fmaxf(fabsf(po - tv.y), 0.f);
            S2 += fmaxf(fabsf(po - tv.z), 0.f);
            S3 += fmaxf(fabsf(po - tv.w), 0.f);
        }
        float Sv[4] = {S0, S1, S2, S3};
        float ps0 = lrow[2] * h, ps1 = lrow[3], pth = lrow[4];   // col3 pre-scaled by w
#pragma unroll
        for (int j = 0; j < 4; ++j) {
            int t = 4 * tg + j;
            float S = Sv[j];
            Sarr[(size_t)(b * T_ + t) * P_ + p] = S;
            float dv = S / clen_s[t];          // needed only for the dist-max
            ldm = fmaxf(ldm, dv);
            float d0 = ps0 - ts0_s[t], d1 = ps1 - ts1_s[t];
            lsm = fmaxf(lsm, sqrtf(d0 * d0 + d1 * d1));
            ltm = fmaxf(ltm, fabsf(pth - tth_s[t]) * 180.f);
        }
        if (tg == 0) {                         // per-p scalars for K2
            float fc[2];
#pragma unroll
            for (int c = 0; c < 2; ++c) {
                float x = lrow[c];
                float pc = 1.f / (1.f + expf(-x));
                float neg = -logf(1.f - pc + 1e-12f) * 0.75f * pc * pc;
                float pos = -logf(pc + 1e-12f) * 0.25f * (1.f - pc) * (1.f - pc);
                fc[c] = pos - neg;
            }
            scal4[(size_t)b * P_ + p] = make_float4(fc[0], fc[1], ps0, ps1);
            pths[(size_t)b * P_ + p] = pth;
        }
    }

    // per-wave shuffle max (fmax order-invariant -> exact), tiny merge
    for (int off = 32; off; off >>= 1) {
        ldm = fmaxf(ldm, __shfl_xor(ldm, off, 64));
        lsm = fmaxf(lsm, __shfl_xor(lsm, off, 64));
        ltm = fmaxf(ltm, __shfl_xor(ltm, off, 64));
    }
    if (lane == 0) { wmax[tg][0] = ldm; wmax[tg][1] = lsm; wmax[tg][2] = ltm; }
    __syncthreads();
    if (tid == 0) {
        float m0 = 0.f, m1 = 0.f, m2 = 0.f;
#pragma unroll
        for (int i = 0; i < 4; ++i) {
            m0 = fmaxf(m0, wmax[i][0]);
            m1 = fmaxf(m1, wmax[i][1]);
            m2 = fmaxf(m2, wmax[i][2]);
        }
        float* q = pmax + (size_t)(b * NXB + bx) * 3;
        q[0] = m0; q[1] = m1; q[2] = m2;
    }
}

// ---------------- K2: block per (b,t) — cost+S to LDS, wave-0 LDS-scan top-4 ----------------
// Early-out for masked-out targets: mk==0 forces dk=0 -> sel all -1 regardless
// of the scans, so ~half the blocks skip all fetch + compute.
__global__ __launch_bounds__(256) void k2(
        const float* __restrict__ targets, const int* __restrict__ masks,
        const int* __restrict__ imgw_p, const int* __restrict__ imgh_p,
        const float* __restrict__ Sarr,
        const float4* __restrict__ scal4, const float* __restrict__ pths,
        const float* __restrict__ pmax, const float* __restrict__ cntg,
        int4* __restrict__ sel, float4* __restrict__ selc) {
    __shared__ float costL[1024];
    __shared__ float SL[1024];

    const int wid = blockIdx.x;              // (b,t)
    const int b = wid >> 4, t = wid & 15;
    const int tid = threadIdx.x;

    const int mk = masks[b * T_ + t];
    if (mk <= 0) {                           // block-uniform: no barrier divergence
        if (tid == 0) {
            sel[wid]  = make_int4(-1, -1, -1, -1);
            selc[wid] = make_float4(BIGC, BIGC, BIGC, BIGC);
        }
        return;
    }

    float dm = 0.f, sm = 0.f, tm = 0.f;
    for (int i = 0; i < NXB; ++i) {
        const float* q = pmax + (size_t)(b * NXB + i) * 3;
        dm = fmaxf(dm, q[0]); sm = fmaxf(sm, q[1]); tm = fmaxf(tm, q[2]);
    }
    dm = fmaxf(dm, 1e-8f); sm = fmaxf(sm, 1e-8f); tm = fmaxf(tm, 1e-8f);

    const float w = (float)(imgw_p[0] - 1);
    const float h = (float)(imgh_p[0] - 1);
    const float* tr = targets + (size_t)(b * T_ + t) * D_;
    const float ts0 = tr[2] * h, ts1 = tr[3] * w, tth = tr[4];
    int lab = (int)tr[1]; lab = lab < 0 ? 0 : (lab > 1 ? 1 : lab);
    const float cntv = cntg[b * T_ + t];
    const float clen = fmaxf(cntv, 1.f);
    const float c30 = 30.f * cntv;

    const float* Srow = Sarr + (size_t)(b * T_ + t) * P_;
    const float4* s4b = scal4 + (size_t)b * P_;
    const float* ptb = pths + (size_t)b * P_;

#pragma unroll
    for (int i = 0; i < 4; ++i) {
        int p = tid + 256 * i;
        if (p < P_) {
            float S = Srow[p];
            float4 s4 = s4b[p];
            float pth = ptb[p];
            float dv = S / clen;                      // == k1's dist, bit-identical
            float dsc = 1.f - dv / dm + 0.01f;
            float d0 = s4.z - ts0, d1 = s4.w - ts1;
            float ssc = 1.f - sqrtf(d0 * d0 + d1 * d1) / sm + 0.01f;
            float tsc = 1.f - fabsf(pth - tth) * 180.f / tm + 0.01f;
            float reg = fmaxf(dsc, 1e-3f) * fmaxf(ssc, 1e-3f) * fmaxf(tsc, 1e-3f);
            float c = -(reg * reg) * 3.f + (lab ? s4.y : s4.x);
            costL[p] = c;                             // mk>0 here: no BIGC override
            SL[p] = S;
        } else {
            costL[p] = INFINITY;
            SL[p] = INFINITY;                          // ascending-S scan sentinel
        }
    }
    __syncthreads();
    if (tid >= 64) return;                   // wave 0 finishes alone

    const int lane = tid;

    // bottom-4 S ascending == top-4 liou descending (liou monotone-dec in S)
    float v0, v1, v2, v3;
#define SROUND(vr) { float bv = INFINITY; int bi = 0x7fffffff;            \
        _Pragma("unroll")                                                 \
        for (int i = 0; i < 16; ++i) { int ix = lane + 64 * i;            \
            float v = SL[ix];                                             \
            if (v < bv || (v == bv && ix < bi)) { bv = v; bi = ix; } }    \
        for (int off = 32; off; off >>= 1) {                              \
            float ov = __shfl_xor(bv, off, 64);                           \
            int oi = __shfl_xor(bi, off, 64);                             \
            if (ov < bv || (ov == bv && oi < bi)) { bv = ov; bi = oi; }   \
        }                                                                 \
        vr = bv; if ((bi & 63) == lane) SL[bi] = INFINITY; }
    SROUND(v0) SROUND(v1) SROUND(v2) SROUND(v3)
#undef SROUND
    float l0 = (c30 - v0) / (c30 + v0 + 1e-9f);
    float l1 = (c30 - v1) / (c30 + v1 + 1e-9f);
    float l2 = (c30 - v2) / (c30 + v2 + 1e-9f);
    float l3 = (c30 - v3) / (c30 + v3 + 1e-9f);
    float sum = ((l0 + l1) + l2) + l3;
    int dk = (int)sum;                 // trunc toward zero == astype(int32)
    if (dk < 1) dk = 1;
    if (dk > 4) dk = 4;

    // top-4 lowest cost (asc, lower-p tie-break == lax.top_k stable)
    int s0, s1, s2, s3;
    float c0, c1, c2, c3;
#define CROUND(sr, cr) { float bv = INFINITY; int bi = 0x7fffffff;        \
        _Pragma("unroll")                                                 \
        for (int i = 0; i < 16; ++i) { int ix = lane + 64 * i;            \
            float v = costL[ix];                                          \
            if (v < bv || (v == bv && ix < bi)) { bv = v; bi = ix; } }    \
        for (int off = 32; off; off >>= 1) {                              \
            float ov = __shfl_xor(bv, off, 64);                           \
            int oi = __shfl_xor(bi, off, 64);                             \
            if (ov < bv || (ov == bv && oi < bi)) { bv = ov; bi = oi; }   \
        }                                                                 \
        sr = bi; cr = bv; if ((bi & 63) == lane) costL[bi] = INFINITY; }
    CROUND(s0, c0) CROUND(s1, c1) CROUND(s2, c2) CROUND(s3, c3)
#undef CROUND

    if (lane == 0) {
        sel[wid]  = make_int4(dk > 0 ? s0 : -1, dk > 1 ? s1 : -1,
                              dk > 2 ? s2 : -1, dk > 3 ? s3 : -1);
        selc[wid] = make_float4(c0, c1, c2, c3);
    }
}

// ---------------- K3: membership + conflict resolution from sel/selc only ----------------
__global__ __launch_bounds__(256) void k3(const int* __restrict__ sel,
                                          const float* __restrict__ selc,
                                          int* __restrict__ out) {
    __shared__ int selE[64];
    __shared__ float selC[64];
    const int b = blockIdx.y, cx = blockIdx.x;
    if (threadIdx.x < 64) {
        selE[threadIdx.x] = sel[b * 64 + threadIdx.x];
        selC[threadIdx.x] = selc[b * 64 + threadIdx.x];
    }
    __syncthreads();

    const int p = cx * 250 + threadIdx.x;
    if (threadIdx.x < 250) {
        int matched = -1;
        float best = INFINITY;
#pragma unroll
        for (int t = 0; t < T_; ++t) {
#pragma unroll
            for (int j = 0; j < 4; ++j) {
                if (selE[4 * t + j] == p) {
                    float c = selC[4 * t + j];
                    if (c < best) { best = c; matched = t; }  // strict <: first-min on t
                }
            }
        }
        out[b * P_ + p] = (matched >= 0) ? 1 : 0;
        out[B_ * P_ + b * P_ + p] = matched;
    }
}

extern "C" void kernel_launch(void* const* d_in, const int* in_sizes, int n_in,
                              void* d_out, int out_size, void* d_ws, size_t ws_size,
                              hipStream_t stream) {
    const float* preds   = (const float*)d_in[0];
    const float* targets = (const float*)d_in[1];
    const int*   masks   = (const int*)d_in[2];
    const int*   imgw    = (const int*)d_in[3];
    const int*   imgh    = (const int*)d_in[4];
    int* out = (int*)d_out;

    char* ws = (char*)d_ws;
    float*  Sarr  = (float*)ws;                        // [B][T][P]  2,048,000 B
    float4* scal4 = (float4*)(ws + 2048000);           // [B][P]       512,000 B
    float*  pths  = (float*)(ws + 2560000);            // [B][P]       128,000 B
    float*  pmax  = (float*)(ws + 2688000);            // [B][NXB][3]    6,144 B
    float*  cntg  = (float*)(ws + 2694144);            // [B][T]         2,048 B
    int4*   sel   = (int4*)(ws + 2696192);             // [B*T]          8,192 B
    float4* selc  = (float4*)(ws + 2704384);           // [B*T]          8,192 B

    k1<<<dim3(NXB, B_), 256, 0, stream>>>(preds, targets, imgw, imgh,
                                          Sarr, scal4, pths, pmax, cntg);
    k2<<<B_ * T_, 256, 0, stream>>>(targets, masks, imgw, imgh, Sarr, scal4, pths,
                                    pmax, cntg, sel, selc);
    k3<<<dim3(4, B_), 256, 0, stream>>>((const int*)sel, (const float*)selc, out);
}

// Round 19
// 33.635 us; speedup vs baseline: 3.8222x; 1.0227x over previous
//
#include <hip/hip_runtime.h>
#include <math.h>

#define B_ 32
#define P_ 1000
#define T_ 16
#define D_ 78
#define O_ 72
#define NXB 16            // p-chunks of 64
#define BIGC 100000000.0f

// ---------------- K1: masked-L1 sums S + per-p scalars + per-block partial maxes ----------------
// (byte-identical to round 18 — verified)
__global__ __launch_bounds__(256) void k1(
        const float* __restrict__ preds, const float* __restrict__ targets,
        const int* __restrict__ imgw_p, const int* __restrict__ imgh_p,
        float* __restrict__ Sarr, float4* __restrict__ scal4, float* __restrict__ pths,
        float* __restrict__ pmax, float* __restrict__ cntg) {
    __shared__ float pred_s[64 * 81];          // 20.7 KB, pad 81 -> conflict-free rows
    __shared__ float tomg[T_ * O_ * 1];        // 4.6 KB  [g*288 + o*4 + j] = to' (NaN if invalid)
    __shared__ float wmax[4][3];
    __shared__ float cnt_s[T_], clen_s[T_], ts0_s[T_], ts1_s[T_], tth_s[T_];

    const int b = blockIdx.y, bx = blockIdx.x;
    const int p0 = bx * 64;
    const int rows = min(64, P_ - p0);
    const int tid = threadIdx.x;
    const float w = (float)(imgw_p[0] - 1);
    const float h = (float)(imgh_p[0] - 1);
    const float imgwf = (float)imgw_p[0];

    {
        const float4* gbase = (const float4*)(preds + ((size_t)b * P_ + p0) * D_);
        const int n4 = rows * D_ / 4;
        for (int i = tid; i < n4; i += 256) {
            float4 v = gbase[i];
            int base = i * 4;
            int r = base / D_, c = base - r * D_;
#pragma unroll
            for (int k = 0; k < 4; ++k) {
                int cc = c + k, rr = r;
                if (cc >= D_) { cc -= D_; ++rr; }
                float x = (&v.x)[k];
                if (cc >= 6 || cc == 3) x *= w;
                pred_s[rr * 81 + cc] = x;
            }
        }
    }
    for (int i = tid; i < T_ * O_; i += 256) {
        int t = i / O_, o = i - t * O_;
        float to = targets[((size_t)b * T_ + t) * D_ + 6 + o] * w;
        bool valid = (to >= 0.f) && (to < imgwf);
        tomg[((t >> 2) * O_ + o) * 4 + (t & 3)] = valid ? to : __int_as_float(0x7fc00000);
    }
    __syncthreads();
    if (tid < T_) {
        int t = tid;
        float c = 0.f;
        for (int o = 0; o < O_; ++o) {
            float to = tomg[((t >> 2) * O_ + o) * 4 + (t & 3)];
            c += (to == to) ? 1.f : 0.f;       // !isnan == valid
        }
        cnt_s[t] = c;
        clen_s[t] = fmaxf(c, 1.f);
        const float* tr = targets + ((size_t)b * T_ + t) * D_;
        ts0_s[t] = tr[2] * h;
        ts1_s[t] = tr[3] * w;
        tth_s[t] = tr[4];
    }
    __syncthreads();

    if (bx == 0 && tid < T_) cntg[b * T_ + tid] = cnt_s[tid];

    const int lane = tid & 63;
    const int tg = tid >> 6;                   // wave = t-group: t = 4tg..4tg+3
    const int p = p0 + lane;

    float ldm = 0.f, lsm = 0.f, ltm = 0.f;
    if (p < P_) {
        const float* lrow = pred_s + lane * 81;
        const float4* tg4 = (const float4*)(tomg + (size_t)tg * O_ * 4);
        float S0 = 0.f, S1 = 0.f, S2 = 0.f, S3 = 0.f;
#pragma unroll 4
        for (int o = 0; o < O_; ++o) {
            float po = lrow[6 + o];
            float4 tv = tg4[o];                // (to'_t0..to'_t3) wave-uniform broadcast
            S0 += fmaxf(fabsf(po - tv.x), 0.f);   // NaN -> 0 (IEEE max)
            S1 += fmaxf(fabsf(po - tv.y), 0.f);
            S2 += fmaxf(fabsf(po - tv.z), 0.f);
            S3 += fmaxf(fabsf(po - tv.w), 0.f);
        }
        float Sv[4] = {S0, S1, S2, S3};
        float ps0 = lrow[2] * h, ps1 = lrow[3], pth = lrow[4];   // col3 pre-scaled by w
#pragma unroll
        for (int j = 0; j < 4; ++j) {
            int t = 4 * tg + j;
            float S = Sv[j];
            Sarr[(size_t)(b * T_ + t) * P_ + p] = S;
            float dv = S / clen_s[t];          // needed only for the dist-max
            ldm = fmaxf(ldm, dv);
            float d0 = ps0 - ts0_s[t], d1 = ps1 - ts1_s[t];
            lsm = fmaxf(lsm, sqrtf(d0 * d0 + d1 * d1));
            ltm = fmaxf(ltm, fabsf(pth - tth_s[t]) * 180.f);
        }
        if (tg == 0) {                         // per-p scalars for K2
            float fc[2];
#pragma unroll
            for (int c = 0; c < 2; ++c) {
                float x = lrow[c];
                float pc = 1.f / (1.f + expf(-x));
                float neg = -logf(1.f - pc + 1e-12f) * 0.75f * pc * pc;
                float pos = -logf(pc + 1e-12f) * 0.25f * (1.f - pc) * (1.f - pc);
                fc[c] = pos - neg;
            }
            scal4[(size_t)b * P_ + p] = make_float4(fc[0], fc[1], ps0, ps1);
            pths[(size_t)b * P_ + p] = pth;
        }
    }

    for (int off = 32; off; off >>= 1) {
        ldm = fmaxf(ldm, __shfl_xor(ldm, off, 64));
        lsm = fmaxf(lsm, __shfl_xor(lsm, off, 64));
        ltm = fmaxf(ltm, __shfl_xor(ltm, off, 64));
    }
    if (lane == 0) { wmax[tg][0] = ldm; wmax[tg][1] = lsm; wmax[tg][2] = ltm; }
    __syncthreads();
    if (tid == 0) {
        float m0 = 0.f, m1 = 0.f, m2 = 0.f;
#pragma unroll
        for (int i = 0; i < 4; ++i) {
            m0 = fmaxf(m0, wmax[i][0]);
            m1 = fmaxf(m1, wmax[i][1]);
            m2 = fmaxf(m2, wmax[i][2]);
        }
        float* q = pmax + (size_t)(b * NXB + bx) * 3;
        q[0] = m0; q[1] = m1; q[2] = m2;
    }
}

// ---------------- K2: block per (b,t) — vectorized phase 0, wave-0 LDS-scan top-4 ----------------
// Phase 0: thread tid<250 owns p = 4*tid..4*tid+3: float4 loads of Srow/pths,
// 4x float4 scal4, single ds_write_b128 per LDS array. Per-element arithmetic
// bit-identical to round 18; only the p->thread mapping changed (no comparator
// depends on it). mk==0 early-out unchanged.
__global__ __launch_bounds__(256) void k2(
        const float* __restrict__ targets, const int* __restrict__ masks,
        const int* __restrict__ imgw_p, const int* __restrict__ imgh_p,
        const float* __restrict__ Sarr,
        const float4* __restrict__ scal4, const float* __restrict__ pths,
        const float* __restrict__ pmax, const float* __restrict__ cntg,
        int4* __restrict__ sel, float4* __restrict__ selc) {
    __shared__ __align__(16) float costL[1024];
    __shared__ __align__(16) float SL[1024];

    const int wid = blockIdx.x;              // (b,t)
    const int b = wid >> 4, t = wid & 15;
    const int tid = threadIdx.x;

    const int mk = masks[b * T_ + t];
    if (mk <= 0) {                           // block-uniform: no barrier divergence
        if (tid == 0) {
            sel[wid]  = make_int4(-1, -1, -1, -1);
            selc[wid] = make_float4(BIGC, BIGC, BIGC, BIGC);
        }
        return;
    }

    float dm = 0.f, sm = 0.f, tm = 0.f;
    for (int i = 0; i < NXB; ++i) {
        const float* q = pmax + (size_t)(b * NXB + i) * 3;
        dm = fmaxf(dm, q[0]); sm = fmaxf(sm, q[1]); tm = fmaxf(tm, q[2]);
    }
    dm = fmaxf(dm, 1e-8f); sm = fmaxf(sm, 1e-8f); tm = fmaxf(tm, 1e-8f);

    const float w = (float)(imgw_p[0] - 1);
    const float h = (float)(imgh_p[0] - 1);
    const float* tr = targets + (size_t)(b * T_ + t) * D_;
    const float ts0 = tr[2] * h, ts1 = tr[3] * w, tth = tr[4];
    int lab = (int)tr[1]; lab = lab < 0 ? 0 : (lab > 1 ? 1 : lab);
    const float cntv = cntg[b * T_ + t];
    const float clen = fmaxf(cntv, 1.f);
    const float c30 = 30.f * cntv;

    const float4* S4  = (const float4*)(Sarr + (size_t)(b * T_ + t) * P_);   // 4000B rows, 16B-aligned
    const float4* pt4 = (const float4*)(pths + (size_t)b * P_);
    const float4* s4b = scal4 + (size_t)b * P_;
    float4* costL4 = (float4*)costL;
    float4* SL4    = (float4*)SL;

    // ---- phase 0: 250 threads x 4 consecutive p, vectorized ----
    if (tid < 250) {
        float4 Sv   = S4[tid];
        float4 pthv = pt4[tid];
        float4 cv, sv;
#pragma unroll
        for (int k = 0; k < 4; ++k) {
            float S   = (&Sv.x)[k];
            float4 s4 = s4b[4 * tid + k];
            float pth = (&pthv.x)[k];
            float dv = S / clen;                      // == k1's dist, bit-identical
            float dsc = 1.f - dv / dm + 0.01f;
            float d0 = s4.z - ts0, d1 = s4.w - ts1;
            float ssc = 1.f - sqrtf(d0 * d0 + d1 * d1) / sm + 0.01f;
            float tsc = 1.f - fabsf(pth - tth) * 180.f / tm + 0.01f;
            float reg = fmaxf(dsc, 1e-3f) * fmaxf(ssc, 1e-3f) * fmaxf(tsc, 1e-3f);
            float c = -(reg * reg) * 3.f + (lab ? s4.y : s4.x);
            (&cv.x)[k] = c;                           // mk>0 here: no BIGC override
            (&sv.x)[k] = S;
        }
        costL4[tid] = cv;
        SL4[tid] = sv;
    } else {
        costL4[tid] = make_float4(INFINITY, INFINITY, INFINITY, INFINITY);
        SL4[tid]    = make_float4(INFINITY, INFINITY, INFINITY, INFINITY);
    }
    __syncthreads();
    if (tid >= 64) return;                   // wave 0 finishes alone

    const int lane = tid;

    // bottom-4 S ascending == top-4 liou descending (liou monotone-dec in S)
    float v0, v1, v2, v3;
#define SROUND(vr) { float bv = INFINITY; int bi = 0x7fffffff;            \
        _Pragma("unroll")                                                 \
        for (int i = 0; i < 16; ++i) { int ix = lane + 64 * i;            \
            float v = SL[ix];                                             \
            if (v < bv || (v == bv && ix < bi)) { bv = v; bi = ix; } }    \
        for (int off = 32; off; off >>= 1) {                              \
            float ov = __shfl_xor(bv, off, 64);                           \
            int oi = __shfl_xor(bi, off, 64);                             \
            if (ov < bv || (ov == bv && oi < bi)) { bv = ov; bi = oi; }   \
        }                                                                 \
        vr = bv; if ((bi & 63) == lane) SL[bi] = INFINITY; }
    SROUND(v0) SROUND(v1) SROUND(v2) SROUND(v3)
#undef SROUND
    float l0 = (c30 - v0) / (c30 + v0 + 1e-9f);
    float l1 = (c30 - v1) / (c30 + v1 + 1e-9f);
    float l2 = (c30 - v2) / (c30 + v2 + 1e-9f);
    float l3 = (c30 - v3) / (c30 + v3 + 1e-9f);
    float sum = ((l0 + l1) + l2) + l3;
    int dk = (int)sum;                 // trunc toward zero == astype(int32)
    if (dk < 1) dk = 1;
    if (dk > 4) dk = 4;

    // top-4 lowest cost (asc, lower-p tie-break == lax.top_k stable)
    int s0, s1, s2, s3;
    float c0, c1, c2, c3;
#define CROUND(sr, cr) { float bv = INFINITY; int bi = 0x7fffffff;        \
        _Pragma("unroll")                                                 \
        for (int i = 0; i < 16; ++i) { int ix = lane + 64 * i;            \
            float v = costL[ix];                                          \
            if (v < bv || (v == bv && ix < bi)) { bv = v; bi = ix; } }    \
        for (int off = 32; off; off >>= 1) {                              \
            float ov = __shfl_xor(bv, off, 64);                           \
            int oi = __shfl_xor(bi, off, 64);                             \
            if (ov < bv || (ov == bv && oi < bi)) { bv = ov; bi = oi; }   \
        }                                                                 \
        sr = bi; cr = bv; if ((bi & 63) == lane) costL[bi] = INFINITY; }
    CROUND(s0, c0) CROUND(s1, c1) CROUND(s2, c2) CROUND(s3, c3)
#undef CROUND

    if (lane == 0) {
        sel[wid]  = make_int4(dk > 0 ? s0 : -1, dk > 1 ? s1 : -1,
                              dk > 2 ? s2 : -1, dk > 3 ? s3 : -1);
        selc[wid] = make_float4(c0, c1, c2, c3);
    }
}

// ---------------- K3: membership + conflict resolution from sel/selc only ----------------
__global__ __launch_bounds__(256) void k3(const int* __restrict__ sel,
                                          const float* __restrict__ selc,
                                          int* __restrict__ out) {
    __shared__ int selE[64];
    __shared__ float selC[64];
    const int b = blockIdx.y, cx = blockIdx.x;
    if (threadIdx.x < 64) {
        selE[threadIdx.x] = sel[b * 64 + threadIdx.x];
        selC[threadIdx.x] = selc[b * 64 + threadIdx.x];
    }
    __syncthreads();

    const int p = cx * 250 + threadIdx.x;
    if (threadIdx.x < 250) {
        int matched = -1;
        float best = INFINITY;
#pragma unroll
        for (int t = 0; t < T_; ++t) {
#pragma unroll
            for (int j = 0; j < 4; ++j) {
                if (selE[4 * t + j] == p) {
                    float c = selC[4 * t + j];
                    if (c < best) { best = c; matched = t; }  // strict <: first-min on t
                }
            }
        }
        out[b * P_ + p] = (matched >= 0) ? 1 : 0;
        out[B_ * P_ + b * P_ + p] = matched;
    }
}

extern "C" void kernel_launch(void* const* d_in, const int* in_sizes, int n_in,
                              void* d_out, int out_size, void* d_ws, size_t ws_size,
                              hipStream_t stream) {
    const float* preds   = (const float*)d_in[0];
    const float* targets = (const float*)d_in[1];
    const int*   masks   = (const int*)d_in[2];
    const int*   imgw    = (const int*)d_in[3];
    const int*   imgh    = (const int*)d_in[4];
    int* out = (int*)d_out;

    char* ws = (char*)d_ws;
    float*  Sarr  = (float*)ws;                        // [B][T][P]  2,048,000 B
    float4* scal4 = (float4*)(ws + 2048000);           // [B][P]       512,000 B
    float*  pths  = (float*)(ws + 2560000);            // [B][P]       128,000 B
    float*  pmax  = (float*)(ws + 2688000);            // [B][NXB][3]    6,144 B
    float*  cntg  = (float*)(ws + 2694144);            // [B][T]         2,048 B
    int4*   sel   = (int4*)(ws + 2696192);             // [B*T]          8,192 B
    float4* selc  = (float4*)(ws + 2704384);           // [B*T]          8,192 B

    k1<<<dim3(NXB, B_), 256, 0, stream>>>(preds, targets, imgw, imgh,
                                          Sarr, scal4, pths, pmax, cntg);
    k2<<<B_ * T_, 256, 0, stream>>>(targets, masks, imgw, imgh, Sarr, scal4, pths,
                                    pmax, cntg, sel, selc);
    k3<<<dim3(4, B_), 256, 0, stream>>>((const int*)sel, (const float*)selc, out);
}

// Round 20
// 32.747 us; speedup vs baseline: 3.9258x; 1.0271x over previous
//
#include <hip/hip_runtime.h>
#include <math.h>

#define B_ 32
#define P_ 1000
#define T_ 16
#define D_ 78
#define O_ 72
#define NXB 16            // p-chunks of 64
#define BIGC 100000000.0f

// ---------------- K1: masked-L1 sums S + per-p scalars + per-block partial maxes ----------------
// 512 threads = 8 waves; wave wv handles t = 2wv, 2wv+1 over the full o-loop.
// Occupancy probe: 16 waves/CU (vs round-19's 8). tomg = NaN-folded single float
// per (t,o), packed as float2 per (t-pair, o) -> one b64 broadcast per o per wave.
// Accumulation chain per (t,p) identical to rounds 18/19 -> S bit-identical.
__global__ __launch_bounds__(512) void k1(
        const float* __restrict__ preds, const float* __restrict__ targets,
        const int* __restrict__ imgw_p, const int* __restrict__ imgh_p,
        float* __restrict__ Sarr, float4* __restrict__ scal4, float* __restrict__ pths,
        float* __restrict__ pmax, float* __restrict__ cntg) {
    __shared__ float pred_s[64 * 81];          // 20.7 KB, pad 81 -> conflict-free rows
    __shared__ float tomg[T_ * O_];            // 4.6 KB  [((t>>1)*O+o)*2 + (t&1)] = to' (NaN if invalid)
    __shared__ float wmax[8][3];
    __shared__ float cnt_s[T_], clen_s[T_], ts0_s[T_], ts1_s[T_], tth_s[T_];

    const int b = blockIdx.y, bx = blockIdx.x;
    const int p0 = bx * 64;
    const int rows = min(64, P_ - p0);
    const int tid = threadIdx.x;
    const float w = (float)(imgw_p[0] - 1);
    const float h = (float)(imgh_p[0] - 1);
    const float imgwf = (float)imgw_p[0];

    // stage preds rows (coalesced float4); scale col 3 and cols>=6 by w
    {
        const float4* gbase = (const float4*)(preds + ((size_t)b * P_ + p0) * D_);
        const int n4 = rows * D_ / 4;
        for (int i = tid; i < n4; i += 512) {
            float4 v = gbase[i];
            int base = i * 4;
            int r = base / D_, c = base - r * D_;
#pragma unroll
            for (int k = 0; k < 4; ++k) {
                int cc = c + k, rr = r;
                if (cc >= D_) { cc -= D_; ++rr; }
                float x = (&v.x)[k];
                if (cc >= 6 || cc == 3) x *= w;
                pred_s[rr * 81 + cc] = x;
            }
        }
    }
    // stage target offsets: to*w if valid else NaN, packed per (t-pair, o)
    for (int i = tid; i < T_ * O_; i += 512) {
        int t = i / O_, o = i - t * O_;
        float to = targets[((size_t)b * T_ + t) * D_ + 6 + o] * w;
        bool valid = (to >= 0.f) && (to < imgwf);
        tomg[((t >> 1) * O_ + o) * 2 + (t & 1)] = valid ? to : __int_as_float(0x7fc00000);
    }
    __syncthreads();
    if (tid < T_) {
        int t = tid;
        float c = 0.f;
        for (int o = 0; o < O_; ++o) {
            float to = tomg[((t >> 1) * O_ + o) * 2 + (t & 1)];
            c += (to == to) ? 1.f : 0.f;       // !isnan == valid
        }
        cnt_s[t] = c;
        clen_s[t] = fmaxf(c, 1.f);
        const float* tr = targets + ((size_t)b * T_ + t) * D_;
        ts0_s[t] = tr[2] * h;
        ts1_s[t] = tr[3] * w;
        tth_s[t] = tr[4];
    }
    __syncthreads();

    if (bx == 0 && tid < T_) cntg[b * T_ + tid] = cnt_s[tid];

    const int lane = tid & 63;
    const int wv = tid >> 6;                   // wave = t-pair: t = 2wv, 2wv+1
    const int p = p0 + lane;

    float ldm = 0.f, lsm = 0.f, ltm = 0.f;
    if (p < P_) {
        const float* lrow = pred_s + lane * 81;
        const float2* tg2 = (const float2*)(tomg + (size_t)wv * O_ * 2);
        float S0 = 0.f, S1 = 0.f;
#pragma unroll 4
        for (int o = 0; o < O_; ++o) {
            float po = lrow[6 + o];
            float2 tv = tg2[o];                // (to'_t0, to'_t1) wave-uniform broadcast
            S0 += fmaxf(fabsf(po - tv.x), 0.f);   // NaN -> 0 (IEEE max)
            S1 += fmaxf(fabsf(po - tv.y), 0.f);
        }
        float Sv[2] = {S0, S1};
        float ps0 = lrow[2] * h, ps1 = lrow[3], pth = lrow[4];   // col3 pre-scaled by w
#pragma unroll
        for (int j = 0; j < 2; ++j) {
            int t = 2 * wv + j;
            float S = Sv[j];
            Sarr[(size_t)(b * T_ + t) * P_ + p] = S;
            float dv = S / clen_s[t];          // needed only for the dist-max
            ldm = fmaxf(ldm, dv);
            float d0 = ps0 - ts0_s[t], d1 = ps1 - ts1_s[t];
            lsm = fmaxf(lsm, sqrtf(d0 * d0 + d1 * d1));
            ltm = fmaxf(ltm, fabsf(pth - tth_s[t]) * 180.f);
        }
        if (wv == 0) {                         // per-p scalars for K2
            float fc[2];
#pragma unroll
            for (int c = 0; c < 2; ++c) {
                float x = lrow[c];
                float pc = 1.f / (1.f + expf(-x));
                float neg = -logf(1.f - pc + 1e-12f) * 0.75f * pc * pc;
                float pos = -logf(pc + 1e-12f) * 0.25f * (1.f - pc) * (1.f - pc);
                fc[c] = pos - neg;
            }
            scal4[(size_t)b * P_ + p] = make_float4(fc[0], fc[1], ps0, ps1);
            pths[(size_t)b * P_ + p] = pth;
        }
    }

    // per-wave shuffle max (fmax order-invariant -> exact), tiny merge
    for (int off = 32; off; off >>= 1) {
        ldm = fmaxf(ldm, __shfl_xor(ldm, off, 64));
        lsm = fmaxf(lsm, __shfl_xor(lsm, off, 64));
        ltm = fmaxf(ltm, __shfl_xor(ltm, off, 64));
    }
    if (lane == 0) { wmax[wv][0] = ldm; wmax[wv][1] = lsm; wmax[wv][2] = ltm; }
    __syncthreads();
    if (tid == 0) {
        float m0 = 0.f, m1 = 0.f, m2 = 0.f;
#pragma unroll
        for (int i = 0; i < 8; ++i) {
            m0 = fmaxf(m0, wmax[i][0]);
            m1 = fmaxf(m1, wmax[i][1]);
            m2 = fmaxf(m2, wmax[i][2]);
        }
        float* q = pmax + (size_t)(b * NXB + bx) * 3;
        q[0] = m0; q[1] = m1; q[2] = m2;
    }
}

// ---------------- K2: block per (b,t) — vectorized phase 0, wave-0 LDS-scan top-4 ----------------
// (byte-identical to round 19 — verified)
__global__ __launch_bounds__(256) void k2(
        const float* __restrict__ targets, const int* __restrict__ masks,
        const int* __restrict__ imgw_p, const int* __restrict__ imgh_p,
        const float* __restrict__ Sarr,
        const float4* __restrict__ scal4, const float* __restrict__ pths,
        const float* __restrict__ pmax, const float* __restrict__ cntg,
        int4* __restrict__ sel, float4* __restrict__ selc) {
    __shared__ __align__(16) float costL[1024];
    __shared__ __align__(16) float SL[1024];

    const int wid = blockIdx.x;              // (b,t)
    const int b = wid >> 4, t = wid & 15;
    const int tid = threadIdx.x;

    const int mk = masks[b * T_ + t];
    if (mk <= 0) {                           // block-uniform: no barrier divergence
        if (tid == 0) {
            sel[wid]  = make_int4(-1, -1, -1, -1);
            selc[wid] = make_float4(BIGC, BIGC, BIGC, BIGC);
        }
        return;
    }

    float dm = 0.f, sm = 0.f, tm = 0.f;
    for (int i = 0; i < NXB; ++i) {
        const float* q = pmax + (size_t)(b * NXB + i) * 3;
        dm = fmaxf(dm, q[0]); sm = fmaxf(sm, q[1]); tm = fmaxf(tm, q[2]);
    }
    dm = fmaxf(dm, 1e-8f); sm = fmaxf(sm, 1e-8f); tm = fmaxf(tm, 1e-8f);

    const float w = (float)(imgw_p[0] - 1);
    const float h = (float)(imgh_p[0] - 1);
    const float* tr = targets + (size_t)(b * T_ + t) * D_;
    const float ts0 = tr[2] * h, ts1 = tr[3] * w, tth = tr[4];
    int lab = (int)tr[1]; lab = lab < 0 ? 0 : (lab > 1 ? 1 : lab);
    const float cntv = cntg[b * T_ + t];
    const float clen = fmaxf(cntv, 1.f);
    const float c30 = 30.f * cntv;

    const float4* S4  = (const float4*)(Sarr + (size_t)(b * T_ + t) * P_);   // 4000B rows, 16B-aligned
    const float4* pt4 = (const float4*)(pths + (size_t)b * P_);
    const float4* s4b = scal4 + (size_t)b * P_;
    float4* costL4 = (float4*)costL;
    float4* SL4    = (float4*)SL;

    // ---- phase 0: 250 threads x 4 consecutive p, vectorized ----
    if (tid < 250) {
        float4 Sv   = S4[tid];
        float4 pthv = pt4[tid];
        float4 cv, sv;
#pragma unroll
        for (int k = 0; k < 4; ++k) {
            float S   = (&Sv.x)[k];
            float4 s4 = s4b[4 * tid + k];
            float pth = (&pthv.x)[k];
            float dv = S / clen;                      // == k1's dist, bit-identical
            float dsc = 1.f - dv / dm + 0.01f;
            float d0 = s4.z - ts0, d1 = s4.w - ts1;
            float ssc = 1.f - sqrtf(d0 * d0 + d1 * d1) / sm + 0.01f;
            float tsc = 1.f - fabsf(pth - tth) * 180.f / tm + 0.01f;
            float reg = fmaxf(dsc, 1e-3f) * fmaxf(ssc, 1e-3f) * fmaxf(tsc, 1e-3f);
            float c = -(reg * reg) * 3.f + (lab ? s4.y : s4.x);
            (&cv.x)[k] = c;                           // mk>0 here: no BIGC override
            (&sv.x)[k] = S;
        }
        costL4[tid] = cv;
        SL4[tid] = sv;
    } else {
        costL4[tid] = make_float4(INFINITY, INFINITY, INFINITY, INFINITY);
        SL4[tid]    = make_float4(INFINITY, INFINITY, INFINITY, INFINITY);
    }
    __syncthreads();
    if (tid >= 64) return;                   // wave 0 finishes alone

    const int lane = tid;

    // bottom-4 S ascending == top-4 liou descending (liou monotone-dec in S)
    float v0, v1, v2, v3;
#define SROUND(vr) { float bv = INFINITY; int bi = 0x7fffffff;            \
        _Pragma("unroll")                                                 \
        for (int i = 0; i < 16; ++i) { int ix = lane + 64 * i;            \
            float v = SL[ix];                                             \
            if (v < bv || (v == bv && ix < bi)) { bv = v; bi = ix; } }    \
        for (int off = 32; off; off >>= 1) {                              \
            float ov = __shfl_xor(bv, off, 64);                           \
            int oi = __shfl_xor(bi, off, 64);                             \
            if (ov < bv || (ov == bv && oi < bi)) { bv = ov; bi = oi; }   \
        }                                                                 \
        vr = bv; if ((bi & 63) == lane) SL[bi] = INFINITY; }
    SROUND(v0) SROUND(v1) SROUND(v2) SROUND(v3)
#undef SROUND
    float l0 = (c30 - v0) / (c30 + v0 + 1e-9f);
    float l1 = (c30 - v1) / (c30 + v1 + 1e-9f);
    float l2 = (c30 - v2) / (c30 + v2 + 1e-9f);
    float l3 = (c30 - v3) / (c30 + v3 + 1e-9f);
    float sum = ((l0 + l1) + l2) + l3;
    int dk = (int)sum;                 // trunc toward zero == astype(int32)
    if (dk < 1) dk = 1;
    if (dk > 4) dk = 4;

    // top-4 lowest cost (asc, lower-p tie-break == lax.top_k stable)
    int s0, s1, s2, s3;
    float c0, c1, c2, c3;
#define CROUND(sr, cr) { float bv = INFINITY; int bi = 0x7fffffff;        \
        _Pragma("unroll")                                                 \
        for (int i = 0; i < 16; ++i) { int ix = lane + 64 * i;            \
            float v = costL[ix];                                          \
            if (v < bv || (v == bv && ix < bi)) { bv = v; bi = ix; } }    \
        for (int off = 32; off; off >>= 1) {                              \
            float ov = __shfl_xor(bv, off, 64);                           \
            int oi = __shfl_xor(bi, off, 64);                             \
            if (ov < bv || (ov == bv && oi < bi)) { bv = ov; bi = oi; }   \
        }                                                                 \
        sr = bi; cr = bv; if ((bi & 63) == lane) costL[bi] = INFINITY; }
    CROUND(s0, c0) CROUND(s1, c1) CROUND(s2, c2) CROUND(s3, c3)
#undef CROUND

    if (lane == 0) {
        sel[wid]  = make_int4(dk > 0 ? s0 : -1, dk > 1 ? s1 : -1,
                              dk > 2 ? s2 : -1, dk > 3 ? s3 : -1);
        selc[wid] = make_float4(c0, c1, c2, c3);
    }
}

// ---------------- K3: membership + conflict resolution from sel/selc only ----------------
__global__ __launch_bounds__(256) void k3(const int* __restrict__ sel,
                                          const float* __restrict__ selc,
                                          int* __restrict__ out) {
    __shared__ int selE[64];
    __shared__ float selC[64];
    const int b = blockIdx.y, cx = blockIdx.x;
    if (threadIdx.x < 64) {
        selE[threadIdx.x] = sel[b * 64 + threadIdx.x];
        selC[threadIdx.x] = selc[b * 64 + threadIdx.x];
    }
    __syncthreads();

    const int p = cx * 250 + threadIdx.x;
    if (threadIdx.x < 250) {
        int matched = -1;
        float best = INFINITY;
#pragma unroll
        for (int t = 0; t < T_; ++t) {
#pragma unroll
            for (int j = 0; j < 4; ++j) {
                if (selE[4 * t + j] == p) {
                    float c = selC[4 * t + j];
                    if (c < best) { best = c; matched = t; }  // strict <: first-min on t
                }
            }
        }
        out[b * P_ + p] = (matched >= 0) ? 1 : 0;
        out[B_ * P_ + b * P_ + p] = matched;
    }
}

extern "C" void kernel_launch(void* const* d_in, const int* in_sizes, int n_in,
                              void* d_out, int out_size, void* d_ws, size_t ws_size,
                              hipStream_t stream) {
    const float* preds   = (const float*)d_in[0];
    const float* targets = (const float*)d_in[1];
    const int*   masks   = (const int*)d_in[2];
    const int*   imgw    = (const int*)d_in[3];
    const int*   imgh    = (const int*)d_in[4];
    int* out = (int*)d_out;

    char* ws = (char*)d_ws;
    float*  Sarr  = (float*)ws;                        // [B][T][P]  2,048,000 B
    float4* scal4 = (float4*)(ws + 2048000);           // [B][P]       512,000 B
    float*  pths  = (float*)(ws + 2560000);            // [B][P]       128,000 B
    float*  pmax  = (float*)(ws + 2688000);            // [B][NXB][3]    6,144 B
    float*  cntg  = (float*)(ws + 2694144);            // [B][T]         2,048 B
    int4*   sel   = (int4*)(ws + 2696192);             // [B*T]          8,192 B
    float4* selc  = (float4*)(ws + 2704384);           // [B*T]          8,192 B

    k1<<<dim3(NXB, B_), 512, 0, stream>>>(preds, targets, imgw, imgh,
                                          Sarr, scal4, pths, pmax, cntg);
    k2<<<B_ * T_, 256, 0, stream>>>(targets, masks, imgw, imgh, Sarr, scal4, pths,
                                    pmax, cntg, sel, selc);
    k3<<<dim3(4, B_), 256, 0, stream>>>((const int*)sel, (const float*)selc, out);
}